// Round 11
// baseline (389.534 us; speedup 1.0000x reference)
//
#include <hip/hip_runtime.h>

// QuantizedSimpleSSM — round 16: R12 pipeline (best, 370us) + two slot-level
// fixes. R15 falsified dbuf a third time (129 vs 120us, VGPR clean -> the
// unroll-2 loop loses ILP and cross-block TLP already hides latency) ->
// all-single-buffer. Fixes here: (1) recur compacted to 64 blocks x 256
// all-active threads (4 chains-of-64/block) — R12's 64-of-256-active recur
// blocks parked 768 idle waves in CU slots D-GEMM waves could use; (2)
// fused_Drec at launch_bounds(256,4), grid 576 — R8 proved gemm at 4/CU is
// ~8% faster and compiles to VGPR 64 unspilled. Same chains, same staged
// bits, same S/R/Y writes -> bitwise (absmax 0.0 since R2).
// Numerics contract: every output element is one fp32 FMA chain in strictly
// ascending k; recurrence mul-then-add + q8.

#define DINX 512
#define LSEQ 512
#define NDIM 512

__device__ __forceinline__ float q8(float x) {
    float xa = fabsf(x);
    float w  = __fadd_rn(xa, 1e-8f);
    int e = (int)((__float_as_uint(w) >> 23) & 0xFFu) - 127;   // floor(log2(w))
    e = e < -7 ? -7 : (e > 7 ? 7 : e);
    float p    = __int_as_float((unsigned)((e + 127) << 23));   // exact 2^e
    float invp = __int_as_float((unsigned)((127 - e) << 23));   // exact 2^-e
    float t  = __fmul_rn(__fsub_rn(__fmul_rn(xa, invp), 1.0f), 8.0f);
    float m  = __fmul_rn(rintf(t), 0.125f);                     // half-to-even
    float r  = __fmul_rn(__fadd_rn(1.0f, m), p);
    return copysignf(r, x);
}

// Bqt[c][r] = q8(B[r][c]); block (0,0) also quants A. grid (16,16), block 256.
__global__ __launch_bounds__(256) void quantBA(const float* __restrict__ B,
                                               const float* __restrict__ A,
                                               float* __restrict__ Bqt,
                                               float* __restrict__ Aq) {
    __shared__ float tl[32][33];
    if (blockIdx.x == 0 && blockIdx.y == 0) {
        Aq[threadIdx.x]       = q8(A[threadIdx.x]);
        Aq[256 + threadIdx.x] = q8(A[256 + threadIdx.x]);
    }
    const int r0 = blockIdx.y * 32, c0 = blockIdx.x * 32;
    const int x = threadIdx.x & 31, y = threadIdx.x >> 5;   // 32 x 8
#pragma unroll
    for (int i = 0; i < 32; i += 8)
        tl[y + i][x] = q8(B[(r0 + y + i) * 512 + c0 + x]);
    __syncthreads();
#pragma unroll
    for (int i = 0; i < 32; i += 8)
        Bqt[(c0 + y + i) * 512 + r0 + x] = tl[x][y + i];
}

// ---------- 8x8 single-buffer GEMM core (R8 bit-exact) ----------
// acc[p][i][q][j] += sum_k X[k][m0 + p*64 + tx*4 + i] * W[k][n0 + q*64 + ty*4 + j]
// k strictly ascending. LDS Xs/Ws [32][128], BK=32 per barrier pair.
__device__ __forceinline__ void gemm_pass(const float* __restrict__ X,
                                          const float* __restrict__ W,
                                          int m0, int n0, int KTOT,
                                          float (&acc)[2][4][2][4],
                                          float (*Xs)[128], float (*Ws)[128],
                                          int tid) {
    const int tx = tid & 15, ty = tid >> 4;
    const int srow = tid >> 4, sseg4 = (tid & 15) * 4;   // 16 rows x 16 chunks
    const float* xp = X + (size_t)srow * 512 + m0 + sseg4;
    const float* wp = W + (size_t)srow * 512 + n0 + sseg4;
    for (int k0 = 0; k0 < KTOT; k0 += 32) {
        float4 x0 = *(const float4*)xp;
        float4 x1 = *(const float4*)(xp + 64);
        float4 x2 = *(const float4*)(xp + 16 * 512);
        float4 x3 = *(const float4*)(xp + 16 * 512 + 64);
        float4 w0 = *(const float4*)wp;
        float4 w1 = *(const float4*)(wp + 64);
        float4 w2 = *(const float4*)(wp + 16 * 512);
        float4 w3 = *(const float4*)(wp + 16 * 512 + 64);
        xp += 32 * 512; wp += 32 * 512;
        __syncthreads();                 // prev-tile reads done before overwrite
        *(float4*)&Xs[srow][sseg4]           = x0;
        *(float4*)&Xs[srow][64 + sseg4]      = x1;
        *(float4*)&Xs[16 + srow][sseg4]      = x2;
        *(float4*)&Xs[16 + srow][64 + sseg4] = x3;
        *(float4*)&Ws[srow][sseg4]           = w0;
        *(float4*)&Ws[srow][64 + sseg4]      = w1;
        *(float4*)&Ws[16 + srow][sseg4]      = w2;
        *(float4*)&Ws[16 + srow][64 + sseg4] = w3;
        __syncthreads();
#pragma unroll
        for (int k = 0; k < 32; ++k) {
            float a[2][4], b[2][4];
            *(float4*)&a[0][0] = *(const float4*)&Xs[k][tx * 4];
            *(float4*)&a[1][0] = *(const float4*)&Xs[k][64 + tx * 4];
            *(float4*)&b[0][0] = *(const float4*)&Ws[k][ty * 4];
            *(float4*)&b[1][0] = *(const float4*)&Ws[k][64 + ty * 4];
#pragma unroll
            for (int p = 0; p < 2; ++p)
#pragma unroll
                for (int i = 0; i < 4; ++i)
#pragma unroll
                    for (int q = 0; q < 2; ++q)
#pragma unroll
                        for (int j = 0; j < 4; ++j)
                            acc[p][i][q][j] = fmaf(a[p][i], b[q][j], acc[p][i][q][j]);
        }
    }
}

// Fused: blocks 0..511 = R-GEMM (8x8); blocks 512..1023 = C/D quant-transpose.
// grid 1024, block 256, 4/CU. (R12-verbatim, proven 122us.)
__global__ __launch_bounds__(256, 4) void fused_RqCD(const float* __restrict__ u,
                                                     const float* __restrict__ Bqt,
                                                     const float* __restrict__ C,
                                                     const float* __restrict__ D,
                                                     float* __restrict__ R,
                                                     float* __restrict__ Cqt,
                                                     float* __restrict__ Dqt) {
    __shared__ float ldsbuf[2 * 32 * 128];   // 32 KB
    const int zz = blockIdx.x;
    const int tid = threadIdx.x;
    if (zz < 512) {
        float (*Xs)[128] = (float(*)[128])ldsbuf;
        float (*Ws)[128] = (float(*)[128])(ldsbuf + 32 * 128);
        const int b = zz & 31, t0 = ((zz >> 5) & 3) * 128, n0 = (zz >> 7) * 128;
        const int tx = tid & 15, ty = tid >> 4;
        const float* ub = u + (size_t)b * (DINX * LSEQ);
        float acc[2][4][2][4] = {};
        gemm_pass(ub, Bqt, t0, n0, DINX, acc, Xs, Ws, tid);
        float* Rb = R + (size_t)b * (LSEQ * NDIM);
#pragma unroll
        for (int p = 0; p < 2; ++p)
#pragma unroll
            for (int i = 0; i < 4; ++i) {
                float* row = Rb + (size_t)(t0 + p * 64 + tx * 4 + i) * NDIM + n0;
                *(float4*)(row + ty * 4)      = make_float4(acc[p][i][0][0], acc[p][i][0][1],
                                                            acc[p][i][0][2], acc[p][i][0][3]);
                *(float4*)(row + 64 + ty * 4) = make_float4(acc[p][i][1][0], acc[p][i][1][1],
                                                            acc[p][i][1][2], acc[p][i][1][3]);
            }
    } else {
        float (*tl)[33] = (float(*)[33])ldsbuf;
        const int d = zz - 512;
        const float* in = (d >> 8) ? D : C;
        float* out      = (d >> 8) ? Dqt : Cqt;
        const int c0 = (d & 15) * 32, r0 = ((d >> 4) & 15) * 32;
        const int x = tid & 31, y = tid >> 5;   // 32 x 8
#pragma unroll
        for (int i = 0; i < 32; i += 8)
            tl[y + i][x] = q8(in[(r0 + y + i) * 512 + c0 + x]);
        __syncthreads();
#pragma unroll
        for (int i = 0; i < 32; i += 8)
            out[(c0 + y + i) * 512 + r0 + x] = tl[x][y + i];
    }
}

// Fused: blocks 0..63 = recurrence COMPACTED (256 threads all active: 4
// chains-of-64 per block; zz = b*2 + half, half covers n0 in {0,256});
// blocks 64..575 = D-GEMM (Pd raw into Y scratch). grid 576, block 256,
// launch_bounds(256,4) -> up to 4 blocks/CU, VGPR cap 128 (R8: compiles ~64).
__global__ __launch_bounds__(256, 4) void fused_Drec(const float* __restrict__ u,
                                                     const float* __restrict__ Dqt,
                                                     const float* __restrict__ R,
                                                     const float* __restrict__ Aq,
                                                     float* __restrict__ Pd,
                                                     float* __restrict__ S) {
    __shared__ float ldsbuf[2 * 32 * 128];   // 32 KB (recur uses 17 KB of it)
    const int zz = blockIdx.x;
    const int tid = threadIdx.x;
    if (zz >= 64) {
        // ---- D-GEMM (R12 bit-exact) ----
        float (*Xs)[128] = (float(*)[128])ldsbuf;
        float (*Ws)[128] = (float(*)[128])(ldsbuf + 32 * 128);
        const int d = zz - 64;
        const int b = d & 31, t0 = ((d >> 5) & 3) * 128, o0 = (d >> 7) * 128;
        const int tx = tid & 15, ty = tid >> 4;
        const float* ub = u + (size_t)b * (DINX * LSEQ);
        float acc[2][4][2][4] = {};
        gemm_pass(ub, Dqt, t0, o0, DINX, acc, Xs, Ws, tid);
        float* Yb = Pd + (size_t)b * (NDIM * LSEQ);
#pragma unroll
        for (int q = 0; q < 2; ++q)
#pragma unroll
            for (int j = 0; j < 4; ++j) {
                float* row = Yb + (size_t)(o0 + q * 64 + ty * 4 + j) * LSEQ + t0;
                *(float4*)(row + tx * 4)      = make_float4(acc[0][0][q][j], acc[0][1][q][j],
                                                            acc[0][2][q][j], acc[0][3][q][j]);
                *(float4*)(row + 64 + tx * 4) = make_float4(acc[1][0][q][j], acc[1][1][q][j],
                                                            acc[1][2][q][j], acc[1][3][q][j]);
            }
    } else {
        // ---- recurrence, compacted: chunk = tid>>6 owns chain n0+n ----
        float (*tile)[16][68] = (float(*)[16][68])ldsbuf;   // [4][16][68], 17 KB
        const int b    = zz >> 1;
        const int half = zz & 1;
        const int ch   = tid >> 6;                  // 0..3
        const int n    = tid & 63;                  // 0..63
        const int n0   = half * 256 + ch * 64;
        const float a = Aq[n0 + n];
        const float* Rb = R + (size_t)b * (LSEQ * NDIM) + n0;
        float* Sb = S + (size_t)b * (NDIM * LSEQ) + (size_t)n0 * LSEQ;
        float s = 0.0f;
        const int c = (n & 3) * 4;
        const int rbase = n >> 2;                   // 0..15
        for (int t0 = 0; t0 < LSEQ; t0 += 16) {
#pragma unroll
            for (int tt = 0; tt < 16; ++tt) {
                float r = Rb[(size_t)(t0 + tt) * NDIM + n];
                s = q8(__fadd_rn(__fmul_rn(s, a), r));
                tile[ch][tt][n] = s;
            }
            __syncthreads();
#pragma unroll
            for (int p = 0; p < 4; ++p) {
                int row = p * 16 + rbase;
                float4 v = make_float4(tile[ch][c + 0][row], tile[ch][c + 1][row],
                                       tile[ch][c + 2][row], tile[ch][c + 3][row]);
                *(float4*)(Sb + (size_t)row * LSEQ + t0 + c) = v;
            }
            __syncthreads();
        }
    }
}

// Y[b][o][t] = q8( (sum_n S[n][t]*Cqt[n][o]) + Pd[b][o][t] ), Pd staged in Y.
// grid (4,4,32), block 256 — R12 bit-exact path.
__global__ __launch_bounds__(256) void gemm_YC(const float* __restrict__ S,
                                               const float* __restrict__ Cqt,
                                               float* __restrict__ Y) {
    __shared__ float Xs[32][128];
    __shared__ float Ws[32][128];
    const int b  = blockIdx.z;
    const int t0 = blockIdx.x * 128, o0 = blockIdx.y * 128;
    const int tid = threadIdx.x;
    const int tx = tid & 15, ty = tid >> 4;
    const float* Sb = S + (size_t)b * (NDIM * LSEQ);
    float acc[2][4][2][4] = {};
    gemm_pass(Sb, Cqt, t0, o0, NDIM, acc, Xs, Ws, tid);

    float* Yb = Y + (size_t)b * (NDIM * LSEQ);
#pragma unroll
    for (int q = 0; q < 2; ++q)
#pragma unroll
        for (int j = 0; j < 4; ++j) {
            float* row = Yb + (size_t)(o0 + q * 64 + ty * 4 + j) * LSEQ + t0;
            float4 v0 = *(const float4*)(row + tx * 4);
            float4 v1 = *(const float4*)(row + 64 + tx * 4);
            *(float4*)(row + tx * 4) =
                make_float4(q8(__fadd_rn(acc[0][0][q][j], v0.x)),
                            q8(__fadd_rn(acc[0][1][q][j], v0.y)),
                            q8(__fadd_rn(acc[0][2][q][j], v0.z)),
                            q8(__fadd_rn(acc[0][3][q][j], v0.w)));
            *(float4*)(row + 64 + tx * 4) =
                make_float4(q8(__fadd_rn(acc[1][0][q][j], v1.x)),
                            q8(__fadd_rn(acc[1][1][q][j], v1.y)),
                            q8(__fadd_rn(acc[1][2][q][j], v1.z)),
                            q8(__fadd_rn(acc[1][3][q][j], v1.w)));
        }
}

extern "C" void kernel_launch(void* const* d_in, const int* in_sizes, int n_in,
                              void* d_out, int out_size, void* d_ws, size_t ws_size,
                              hipStream_t stream) {
    const float* u = (const float*)d_in[0];   // (32, 512, 512)
    const float* A = (const float*)d_in[1];   // (512,)
    const float* B = (const float*)d_in[2];   // (512, 512)
    const float* C = (const float*)d_in[3];   // (512, 512)
    const float* D = (const float*)d_in[4];   // (512, 512)

    float* ws  = (float*)d_ws;
    float* Aq  = ws;                    // 512
    float* Bqt = Aq + 512;              // 262144  [d][n]
    float* Cqt = Bqt + 262144;          // 262144  [n][o]
    float* Dqt = Cqt + 262144;          // 262144  [d][o]
    float* R   = Dqt + 262144;          // 8388608 [b][t][n]
    float* S   = R + 8388608;           // 8388608 [b][n][t]
    float* Y   = (float*)d_out;         // 8388608 [b][o][t] (also Pd scratch)

    quantBA<<<dim3(16, 16), 256, 0, stream>>>(B, A, Bqt, Aq);
    fused_RqCD<<<1024, 256, 0, stream>>>(u, Bqt, C, D, R, Cqt, Dqt);
    fused_Drec<<<576, 256, 0, stream>>>(u, Dqt, R, Aq, Y, S);
    gemm_YC<<<dim3(4, 4, 32), 256, 0, stream>>>(S, Cqt, Y);
}

// Round 12
// 375.623 us; speedup vs baseline: 1.0370x; 1.0370x over previous
//
#include <hip/hip_runtime.h>

// QuantizedSimpleSSM — round 17: restore R12 verbatim (session best, 370us).
// R16's slot fixes regressed (132 vs 120us Drec; compacted recur added 42MB
// write anomaly; grid 576 diluted D co-residency) -> full revert.
// FINAL-STATE ANALYSIS: the 8x8-tile single-buffer GEMM at max blocks/CU is
// the structural optimum for this bitwise-fp32 contract. Per CU per GEMM:
// DS-pipe (one shared LDS pipe/CU) demand 208k cyc vs VALU 262k/4-SIMDs ->
// DS-bound 1.5x; balancing needs per-thread tile m*n >= 6(m+n) (>=144 acc
// VGPRs -> 1 wave/SIMD -> TLP collapse, measured R10/R14). Measured LDS-pipe
// util ~83%; 10 rounds of occupancy/dbuf/prefetch/BK/scalar-pipe variations
// all failed to exceed it (ledger in session journal). Pipeline has no
// remaining dependency-free serialization (recur hides under D; quantCD under
// R; recur-split loses to half-grid occupancy dilution).
// Numerics contract (absmax 0.0 since R2): every output element is one fp32
// FMA chain in strictly ascending k; recurrence mul-then-add + q8.

#define DINX 512
#define LSEQ 512
#define NDIM 512

__device__ __forceinline__ float q8(float x) {
    float xa = fabsf(x);
    float w  = __fadd_rn(xa, 1e-8f);
    int e = (int)((__float_as_uint(w) >> 23) & 0xFFu) - 127;   // floor(log2(w))
    e = e < -7 ? -7 : (e > 7 ? 7 : e);
    float p    = __int_as_float((unsigned)((e + 127) << 23));   // exact 2^e
    float invp = __int_as_float((unsigned)((127 - e) << 23));   // exact 2^-e
    float t  = __fmul_rn(__fsub_rn(__fmul_rn(xa, invp), 1.0f), 8.0f);
    float m  = __fmul_rn(rintf(t), 0.125f);                     // half-to-even
    float r  = __fmul_rn(__fadd_rn(1.0f, m), p);
    return copysignf(r, x);
}

// Bqt[c][r] = q8(B[r][c]); block (0,0) also quants A. grid (16,16), block 256.
__global__ __launch_bounds__(256) void quantBA(const float* __restrict__ B,
                                               const float* __restrict__ A,
                                               float* __restrict__ Bqt,
                                               float* __restrict__ Aq) {
    __shared__ float tl[32][33];
    if (blockIdx.x == 0 && blockIdx.y == 0) {
        Aq[threadIdx.x]       = q8(A[threadIdx.x]);
        Aq[256 + threadIdx.x] = q8(A[256 + threadIdx.x]);
    }
    const int r0 = blockIdx.y * 32, c0 = blockIdx.x * 32;
    const int x = threadIdx.x & 31, y = threadIdx.x >> 5;   // 32 x 8
#pragma unroll
    for (int i = 0; i < 32; i += 8)
        tl[y + i][x] = q8(B[(r0 + y + i) * 512 + c0 + x]);
    __syncthreads();
#pragma unroll
    for (int i = 0; i < 32; i += 8)
        Bqt[(c0 + y + i) * 512 + r0 + x] = tl[x][y + i];
}

// 8x8 per-thread tile (R8 bit-exact path).
// acc[p][i][q][j] += sum_k X[k][m0 + p*64 + tx*4 + i] * W[k][n0 + q*64 + ty*4 + j]
// k strictly ascending. LDS Xs/Ws [32][128], BK=32 per barrier pair.
__device__ __forceinline__ void gemm_pass(const float* __restrict__ X,
                                          const float* __restrict__ W,
                                          int m0, int n0, int KTOT,
                                          float (&acc)[2][4][2][4],
                                          float (*Xs)[128], float (*Ws)[128],
                                          int tid) {
    const int tx = tid & 15, ty = tid >> 4;
    const int srow = tid >> 4, sseg4 = (tid & 15) * 4;   // 16 rows x 16 chunks
    const float* xp = X + (size_t)srow * 512 + m0 + sseg4;
    const float* wp = W + (size_t)srow * 512 + n0 + sseg4;
    for (int k0 = 0; k0 < KTOT; k0 += 32) {
        float4 x0 = *(const float4*)xp;
        float4 x1 = *(const float4*)(xp + 64);
        float4 x2 = *(const float4*)(xp + 16 * 512);
        float4 x3 = *(const float4*)(xp + 16 * 512 + 64);
        float4 w0 = *(const float4*)wp;
        float4 w1 = *(const float4*)(wp + 64);
        float4 w2 = *(const float4*)(wp + 16 * 512);
        float4 w3 = *(const float4*)(wp + 16 * 512 + 64);
        xp += 32 * 512; wp += 32 * 512;
        __syncthreads();                 // prev-tile reads done before overwrite
        *(float4*)&Xs[srow][sseg4]           = x0;
        *(float4*)&Xs[srow][64 + sseg4]      = x1;
        *(float4*)&Xs[16 + srow][sseg4]      = x2;
        *(float4*)&Xs[16 + srow][64 + sseg4] = x3;
        *(float4*)&Ws[srow][sseg4]           = w0;
        *(float4*)&Ws[srow][64 + sseg4]      = w1;
        *(float4*)&Ws[16 + srow][sseg4]      = w2;
        *(float4*)&Ws[16 + srow][64 + sseg4] = w3;
        __syncthreads();
#pragma unroll
        for (int k = 0; k < 32; ++k) {
            float a[2][4], b[2][4];
            *(float4*)&a[0][0] = *(const float4*)&Xs[k][tx * 4];
            *(float4*)&a[1][0] = *(const float4*)&Xs[k][64 + tx * 4];
            *(float4*)&b[0][0] = *(const float4*)&Ws[k][ty * 4];
            *(float4*)&b[1][0] = *(const float4*)&Ws[k][64 + ty * 4];
#pragma unroll
            for (int p = 0; p < 2; ++p)
#pragma unroll
                for (int i = 0; i < 4; ++i)
#pragma unroll
                    for (int q = 0; q < 2; ++q)
#pragma unroll
                        for (int j = 0; j < 4; ++j)
                            acc[p][i][q][j] = fmaf(a[p][i], b[q][j], acc[p][i][q][j]);
        }
    }
}

// Fused: blocks 0..511 = R-GEMM (R[b][t][n] = sum_d u[b][d][t]*Bqt[d][n]);
// blocks 512..1023 = C/D quant-transpose (independent, needed only later).
// grid 1024, block 256, 4 blocks/CU.
__global__ __launch_bounds__(256, 4) void fused_RqCD(const float* __restrict__ u,
                                                     const float* __restrict__ Bqt,
                                                     const float* __restrict__ C,
                                                     const float* __restrict__ D,
                                                     float* __restrict__ R,
                                                     float* __restrict__ Cqt,
                                                     float* __restrict__ Dqt) {
    __shared__ float ldsbuf[2 * 32 * 128];   // 32 KB
    const int zz = blockIdx.x;
    const int tid = threadIdx.x;
    if (zz < 512) {
        float (*Xs)[128] = (float(*)[128])ldsbuf;
        float (*Ws)[128] = (float(*)[128])(ldsbuf + 32 * 128);
        const int b = zz & 31, t0 = ((zz >> 5) & 3) * 128, n0 = (zz >> 7) * 128;
        const int tx = tid & 15, ty = tid >> 4;
        const float* ub = u + (size_t)b * (DINX * LSEQ);
        float acc[2][4][2][4] = {};
        gemm_pass(ub, Bqt, t0, n0, DINX, acc, Xs, Ws, tid);
        float* Rb = R + (size_t)b * (LSEQ * NDIM);
#pragma unroll
        for (int p = 0; p < 2; ++p)
#pragma unroll
            for (int i = 0; i < 4; ++i) {
                float* row = Rb + (size_t)(t0 + p * 64 + tx * 4 + i) * NDIM + n0;
                *(float4*)(row + ty * 4)      = make_float4(acc[p][i][0][0], acc[p][i][0][1],
                                                            acc[p][i][0][2], acc[p][i][0][3]);
                *(float4*)(row + 64 + ty * 4) = make_float4(acc[p][i][1][0], acc[p][i][1][1],
                                                            acc[p][i][1][2], acc[p][i][1][3]);
            }
    } else {
        float (*tl)[33] = (float(*)[33])ldsbuf;
        const int d = zz - 512;
        const float* in = (d >> 8) ? D : C;
        float* out      = (d >> 8) ? Dqt : Cqt;
        const int c0 = (d & 15) * 32, r0 = ((d >> 4) & 15) * 32;
        const int x = tid & 31, y = tid >> 5;   // 32 x 8
#pragma unroll
        for (int i = 0; i < 32; i += 8)
            tl[y + i][x] = q8(in[(r0 + y + i) * 512 + c0 + x]);
        __syncthreads();
#pragma unroll
        for (int i = 0; i < 32; i += 8)
            out[(c0 + y + i) * 512 + r0 + x] = tl[x][y + i];
    }
}

// Fused: blocks 0..255 = recurrence (dispatch first -> ~1/CU, hidden under D);
// blocks 256..767 = D-GEMM (Pd[b][o][t] = sum_d u[b][d][t]*Dqt[d][o], raw into
// Y scratch). grid 768, block 256, 3 blocks/CU (12 waves: 8 D + 4 recur).
__global__ __launch_bounds__(256, 3) void fused_Drec(const float* __restrict__ u,
                                                     const float* __restrict__ Dqt,
                                                     const float* __restrict__ R,
                                                     const float* __restrict__ Aq,
                                                     float* __restrict__ Pd,
                                                     float* __restrict__ S) {
    __shared__ float ldsbuf[2 * 32 * 128];   // 32 KB
    const int zz = blockIdx.x;
    const int tid = threadIdx.x;
    if (zz >= 256) {
        // ---- D-GEMM (R8 bit-exact else-branch) ----
        float (*Xs)[128] = (float(*)[128])ldsbuf;
        float (*Ws)[128] = (float(*)[128])(ldsbuf + 32 * 128);
        const int d = zz - 256;
        const int b = d & 31, t0 = ((d >> 5) & 3) * 128, o0 = (d >> 7) * 128;
        const int tx = tid & 15, ty = tid >> 4;
        const float* ub = u + (size_t)b * (DINX * LSEQ);
        float acc[2][4][2][4] = {};
        gemm_pass(ub, Dqt, t0, o0, DINX, acc, Xs, Ws, tid);
        float* Yb = Pd + (size_t)b * (NDIM * LSEQ);
#pragma unroll
        for (int q = 0; q < 2; ++q)
#pragma unroll
            for (int j = 0; j < 4; ++j) {
                float* row = Yb + (size_t)(o0 + q * 64 + ty * 4 + j) * LSEQ + t0;
                *(float4*)(row + tx * 4)      = make_float4(acc[0][0][q][j], acc[0][1][q][j],
                                                            acc[0][2][q][j], acc[0][3][q][j]);
                *(float4*)(row + 64 + tx * 4) = make_float4(acc[1][0][q][j], acc[1][1][q][j],
                                                            acc[1][2][q][j], acc[1][3][q][j]);
            }
    } else {
        // ---- recurrence (bit-exact chain; tid<64 active, all barrier) ----
        float (*tile)[68] = (float(*)[68])ldsbuf;
        const int b  = zz >> 3;
        const int n0 = (zz & 7) * 64;
        const int n  = tid & 63;
        const bool act = tid < 64;
        float a = 0.0f, s = 0.0f;
        const float* Rb = R + (size_t)b * (LSEQ * NDIM) + n0;
        float* Sb = S + (size_t)b * (NDIM * LSEQ) + (size_t)n0 * LSEQ;
        if (act) a = Aq[n0 + n];
        const int c = (n & 3) * 4;
        const int rbase = n >> 2;                   // 0..15
        for (int t0 = 0; t0 < LSEQ; t0 += 16) {
            if (act) {
#pragma unroll
                for (int tt = 0; tt < 16; ++tt) {
                    float r = Rb[(size_t)(t0 + tt) * NDIM + n];
                    s = q8(__fadd_rn(__fmul_rn(s, a), r));
                    tile[tt][n] = s;
                }
            }
            __syncthreads();
            if (act) {
#pragma unroll
                for (int p = 0; p < 4; ++p) {
                    int row = p * 16 + rbase;
                    float4 v = make_float4(tile[c + 0][row], tile[c + 1][row],
                                           tile[c + 2][row], tile[c + 3][row]);
                    *(float4*)(Sb + (size_t)row * LSEQ + t0 + c) = v;
                }
            }
            __syncthreads();
        }
    }
}

// Y[b][o][t] = q8( (sum_n S[n][t]*Cqt[n][o]) + Pd[b][o][t] ), Pd staged in Y.
// grid (4,4,32), block 256 — R8/R11 bit-exact path.
__global__ __launch_bounds__(256) void gemm_YC(const float* __restrict__ S,
                                               const float* __restrict__ Cqt,
                                               float* __restrict__ Y) {
    __shared__ float Xs[32][128];
    __shared__ float Ws[32][128];
    const int b  = blockIdx.z;
    const int t0 = blockIdx.x * 128, o0 = blockIdx.y * 128;
    const int tid = threadIdx.x;
    const int tx = tid & 15, ty = tid >> 4;
    const float* Sb = S + (size_t)b * (NDIM * LSEQ);
    float acc[2][4][2][4] = {};
    gemm_pass(Sb, Cqt, t0, o0, NDIM, acc, Xs, Ws, tid);

    float* Yb = Y + (size_t)b * (NDIM * LSEQ);
#pragma unroll
    for (int q = 0; q < 2; ++q)
#pragma unroll
        for (int j = 0; j < 4; ++j) {
            float* row = Yb + (size_t)(o0 + q * 64 + ty * 4 + j) * LSEQ + t0;
            float4 v0 = *(const float4*)(row + tx * 4);
            float4 v1 = *(const float4*)(row + 64 + tx * 4);
            *(float4*)(row + tx * 4) =
                make_float4(q8(__fadd_rn(acc[0][0][q][j], v0.x)),
                            q8(__fadd_rn(acc[0][1][q][j], v0.y)),
                            q8(__fadd_rn(acc[0][2][q][j], v0.z)),
                            q8(__fadd_rn(acc[0][3][q][j], v0.w)));
            *(float4*)(row + 64 + tx * 4) =
                make_float4(q8(__fadd_rn(acc[1][0][q][j], v1.x)),
                            q8(__fadd_rn(acc[1][1][q][j], v1.y)),
                            q8(__fadd_rn(acc[1][2][q][j], v1.z)),
                            q8(__fadd_rn(acc[1][3][q][j], v1.w)));
        }
}

extern "C" void kernel_launch(void* const* d_in, const int* in_sizes, int n_in,
                              void* d_out, int out_size, void* d_ws, size_t ws_size,
                              hipStream_t stream) {
    const float* u = (const float*)d_in[0];   // (32, 512, 512)
    const float* A = (const float*)d_in[1];   // (512,)
    const float* B = (const float*)d_in[2];   // (512, 512)
    const float* C = (const float*)d_in[3];   // (512, 512)
    const float* D = (const float*)d_in[4];   // (512, 512)

    float* ws  = (float*)d_ws;
    float* Aq  = ws;                    // 512
    float* Bqt = Aq + 512;              // 262144  [d][n]
    float* Cqt = Bqt + 262144;          // 262144  [n][o]
    float* Dqt = Cqt + 262144;          // 262144  [d][o]
    float* R   = Dqt + 262144;          // 8388608 [b][t][n]
    float* S   = R + 8388608;           // 8388608 [b][n][t]
    float* Y   = (float*)d_out;         // 8388608 [b][o][t] (also Pd scratch)

    quantBA<<<dim3(16, 16), 256, 0, stream>>>(B, A, Bqt, Aq);
    fused_RqCD<<<1024, 256, 0, stream>>>(u, Bqt, C, D, R, Cqt, Dqt);
    fused_Drec<<<768, 256, 0, stream>>>(u, Dqt, R, Aq, Y, S);
    gemm_YC<<<dim3(4, 4, 32), 256, 0, stream>>>(S, Cqt, Y);
}